// Round 8
// baseline (8483.841 us; speedup 1.0000x reference)
//
#include <hip/hip_runtime.h>
#include <stdint.h>

#define E_DIM 2048
#define H_DIM 2048
#define B_DIM 512
#define T_DIM 256
#define G4H   8192  // 4*H

typedef unsigned short u16;
typedef __attribute__((ext_vector_type(8))) short bf16x8;
typedef __attribute__((ext_vector_type(4))) float f32x4;
typedef __attribute__((ext_vector_type(16))) float f32x16;

__device__ inline u16 f2b(float f) {
  union { float f; uint32_t i; } v; v.f = f;
  uint32_t u = v.i;
  return (u16)((u + 0x7FFFu + ((u >> 16) & 1u)) >> 16);  // RNE
}
__device__ inline float b2f(u16 u) {
  union { uint32_t i; float f; } v; v.i = ((uint32_t)u) << 16; return v.f;
}

__global__ __launch_bounds__(256) void convert_bf16(const float* __restrict__ s,
                                                    u16* __restrict__ d, int n4) {
  int i = blockIdx.x * 256 + threadIdx.x;
  if (i < n4) {
    float4 f = ((const float4*)s)[i];
    ushort4 o;
    o.x = f2b(f.x); o.y = f2b(f.y); o.z = f2b(f.z); o.w = f2b(f.w);
    ((ushort4*)d)[i] = o;
  }
}

// W_eff = W_hh + W_ih @ W_out (rank-2 fold), 32x32x16-MFMA B-fragment order.
// Chunk id = (n32*128 + k16)*64 + lane holds 8 bf16 of
//   B[n' = n32*32 + (lane&31)][k = k16*16 + (lane>>5)*8 + j]
// n' gate-interleaved: n' = jrow*4 + g  <- row g*H + jrow.
__global__ __launch_bounds__(256) void build_weff(const float* __restrict__ W,
                                                  const float* __restrict__ W_ih,
                                                  const float* __restrict__ W_out,
                                                  u16* __restrict__ Wz) {
  int id = blockIdx.x * 256 + threadIdx.x;     // chunk id, total 2M
  int lane = id & 63;
  int k16  = (id >> 6) & 127;
  int n32  = id >> 13;                         // 0..255
  int np = n32 * 32 + (lane & 31);
  int k  = k16 * 16 + (lane >> 5) * 8;
  int g = np & 3, jrow = np >> 2;
  int src = g * H_DIM + jrow;
  float wi0 = W_ih[src * 2 + 0], wi1 = W_ih[src * 2 + 1];
  const float* sw = W + (size_t)src * H_DIM + k;
  u16 out[8];
  for (int j = 0; j < 8; ++j) {
    float v = sw[j] + wi0 * W_out[k + j] + wi1 * W_out[H_DIM + k + j];
    out[j] = f2b(v);
  }
  u16* dst = Wz + (size_t)id * 8;
  *(ushort4*)(dst) = *(ushort4*)&out[0];
  *(ushort4*)(dst + 4) = *(ushort4*)&out[4];
}

// epi[n'] = {b_ih+b_hh+b_out@W_ih^T, W_ih[:,0], W_ih[:,1], 0}   [verified r5-r7]
__global__ __launch_bounds__(256) void build_epi(const float* __restrict__ b_ih,
                                                 const float* __restrict__ b_hh,
                                                 const float* __restrict__ W_ih,
                                                 const float* __restrict__ b_out,
                                                 float* __restrict__ epi) {
  int np = blockIdx.x * 256 + threadIdx.x;
  int src = (np & 3) * H_DIM + (np >> 2);
  float wi0 = W_ih[src * 2 + 0], wi1 = W_ih[src * 2 + 1];
  float4 e;
  e.x = b_ih[src] + b_hh[src] + b_out[0] * wi0 + b_out[1] * wi1;
  e.y = wi0;
  e.z = wi1;
  e.w = 0.f;
  ((float4*)epi)[np] = e;
}

// ---- plain GEMM (h0 path, runs once) ----
#define BM 64
#define BN 128
#define BK 32
__global__ __launch_bounds__(256) void gemm_bt(const u16* __restrict__ A,
                                               const u16* __restrict__ Bm,
                                               float* __restrict__ C,
                                               int M, int N, int K) {
  __shared__ u16 sA[BM * BK];
  __shared__ u16 sB[BN * BK];
  const int t = threadIdx.x;
  const int bm0 = blockIdx.y * BM, bn0 = blockIdx.x * BN;
  const int wave = t >> 6, lane = t & 63;
  const int wm = (wave >> 1) * 32, wn = (wave & 1) * 64;
  const int r16 = lane & 15, quad = lane >> 4;

  f32x4 acc[2][4];
  const f32x4 z = {0.f, 0.f, 0.f, 0.f};
  for (int i = 0; i < 2; ++i)
    for (int j = 0; j < 4; ++j) acc[i][j] = z;

  const int arow = t >> 2, acg = t & 3;

  for (int k0 = 0; k0 < K; k0 += BK) {
    __syncthreads();
    *(uint4*)&sA[arow * BK + acg * 8] =
        *(const uint4*)&A[(size_t)(bm0 + arow) * K + k0 + acg * 8];
    for (int i = 0; i < 2; ++i) {
      int c = t + 256 * i;
      int row = c >> 2, cg = c & 3;
      *(uint4*)&sB[row * BK + cg * 8] =
          *(const uint4*)&Bm[(size_t)(bn0 + row) * K + k0 + cg * 8];
    }
    __syncthreads();
    bf16x8 af[2], bfr[4];
    for (int mt = 0; mt < 2; ++mt)
      af[mt] = *(const bf16x8*)&sA[(wm + mt * 16 + r16) * BK + quad * 8];
    for (int nt = 0; nt < 4; ++nt)
      bfr[nt] = *(const bf16x8*)&sB[(wn + nt * 16 + r16) * BK + quad * 8];
    for (int mt = 0; mt < 2; ++mt)
      for (int nt = 0; nt < 4; ++nt)
        acc[mt][nt] = __builtin_amdgcn_mfma_f32_16x16x32_bf16(af[mt], bfr[nt],
                                                              acc[mt][nt], 0, 0, 0);
  }
  for (int mt = 0; mt < 2; ++mt)
    for (int nt = 0; nt < 4; ++nt) {
      int row = bm0 + wm + mt * 16 + quad * 4;
      int col = bn0 + wn + nt * 16 + r16;
      for (int r = 0; r < 4; ++r)
        C[(size_t)(row + r) * N + col] = acc[mt][nt][r];
    }
}

// h0pre + b_embed -> h in 32x32-fragment layout; c=0; xzero=0.
// pos(m,k) = (((m>>5)*128 + (k>>4))*64 + ((k>>3)&1)*32 + (m&31))*8 + (k&7)
__global__ __launch_bounds__(256) void init_state(const float* __restrict__ h0pre,
                                                  const float* __restrict__ b_embed,
                                                  u16* __restrict__ h,
                                                  float* __restrict__ c,
                                                  float* __restrict__ xzero) {
  int idx = blockIdx.x * 256 + threadIdx.x;  // B*H
  int bg = idx >> 11, k = idx & (H_DIM - 1);
  float v = h0pre[idx] + b_embed[k];
  size_t chunk = (((size_t)(bg >> 5)) * 128 + (k >> 4)) * 64 + ((k >> 3) & 1) * 32 + (bg & 31);
  size_t pos = chunk * 8 + (k & 7);
  h[pos] = f2b(v);
  c[pos] = 0.f;
  if (idx < B_DIM * 2) xzero[idx] = 0.f;
}

// xcorr[m] = -(h0[m] @ W_out^T + b_out)   [verified r5-r7]
__global__ __launch_bounds__(64) void calc_xcorr(const float* __restrict__ h0pre,
                                                 const float* __restrict__ b_embed,
                                                 const float* __restrict__ W_out,
                                                 const float* __restrict__ b_out,
                                                 float* __restrict__ xc) {
  int m = blockIdx.x, ln = threadIdx.x;
  float s0 = 0.f, s1 = 0.f;
  for (int k = ln; k < H_DIM; k += 64) {
    float hv = h0pre[(size_t)m * H_DIM + k] + b_embed[k];
    s0 += hv * W_out[k];
    s1 += hv * W_out[H_DIM + k];
  }
  for (int off = 32; off > 0; off >>= 1) {
    s0 += __shfl_down(s0, off);
    s1 += __shfl_down(s1, off);
  }
  if (ln == 0) {
    xc[m * 2 + 0] = -(s0 + b_out[0]);
    xc[m * 2 + 1] = -(s1 + b_out[1]);
  }
}

__global__ __launch_bounds__(256) void init_out(const float* __restrict__ b_out,
                                                const float* __restrict__ b_stop,
                                                float* __restrict__ coords,
                                                float* __restrict__ stops) {
  int i = blockIdx.x * 256 + threadIdx.x;      // B*T
  coords[i * 2 + 0] = b_out[0];
  coords[i * 2 + 1] = b_out[1];
  stops[i] = b_stop[0];
}

__global__ __launch_bounds__(256) void finalize_stops(float* __restrict__ stops) {
  int i = blockIdx.x * 256 + threadIdx.x;      // B*T
  stops[i] = 1.f / (1.f + __expf(-stops[i]));
}

// ---- fused step: 128x64 wave tiles via 32x32x16 MFMA, 4-way K-split ----
// 8 waves: wn2 = wv&1 (n-half, 2 n32-tiles), kq = wv>>1 (K quarter).
// Per wave per k16: 4 A-frags + 2 B-frags -> 8 MFMA. ~190 VGPRs (no spill).
__global__ __launch_bounds__(512) void gemm_lstm(const u16* __restrict__ hA,
                                                 const u16* __restrict__ Wz,
                                                 const float* __restrict__ epi,
                                                 const float* __restrict__ x,
                                                 float* __restrict__ c,
                                                 u16* __restrict__ h_out,
                                                 const float* __restrict__ W_out,
                                                 const float* __restrict__ W_stop,
                                                 float* __restrict__ coords,
                                                 float* __restrict__ stops,
                                                 int trow) {
  __shared__ char smem[131072];                // combine bufs; gt aliased
  float* cb = (float*)smem;
  float* gt = (float*)smem;                    // 64 x 132 f32 epilogue tile

  const int bid = blockIdx.x;
  const int nt = (bid & 7) * 8 + ((bid >> 3) & 7);   // XCD-pinned n-tile (128 cols)
  const int mt = bid >> 6;
  const int bm0 = mt * 128;

  const int t = threadIdx.x, wv = t >> 6, ln = t & 63;
  const int wn2 = wv & 1, kq = wv >> 1;
  const int r16 = ln & 15, quad = ln >> 4;

  // fragment pointers (u16 units); per-k16 stride = 512
  const u16* pA[4];
  const u16* pB[2];
  for (int i = 0; i < 4; ++i)
    pA[i] = hA + ((size_t)(mt * 4 + i) * 128 + kq * 32) * 512 + ln * 8;
  for (int i = 0; i < 2; ++i)
    pB[i] = Wz + ((size_t)(nt * 4 + wn2 * 2 + i) * 128 + kq * 32) * 512 + ln * 8;

  f32x16 acc[4][2];
  for (int i = 0; i < 4; ++i)
    for (int j = 0; j < 2; ++j)
      for (int r = 0; r < 16; ++r) acc[i][j][r] = 0.f;

  bf16x8 af[2][4], bf[2][2];
  for (int i = 0; i < 4; ++i) af[0][i] = *(const bf16x8*)(pA[i]);
  for (int i = 0; i < 2; ++i) bf[0][i] = *(const bf16x8*)(pB[i]);

#pragma unroll 2
  for (int kk = 0; kk < 32; ++kk) {
    const int cu = kk & 1;
    if (kk < 31) {
      const int nx = cu ^ 1;
      const size_t off = (size_t)(kk + 1) * 512;
      for (int i = 0; i < 4; ++i) af[nx][i] = *(const bf16x8*)(pA[i] + off);
      for (int i = 0; i < 2; ++i) bf[nx][i] = *(const bf16x8*)(pB[i] + off);
    }
    for (int mi = 0; mi < 4; ++mi)
      for (int ni = 0; ni < 2; ++ni)
        acc[mi][ni] = __builtin_amdgcn_mfma_f32_32x32x16_bf16(af[cu][mi], bf[cu][ni],
                                                              acc[mi][ni], 0, 0, 0);
  }

  // K-combine round 1: kq 2,3 export (4 x 32 KB), kq 0,1 add
  if (kq >= 2) {
    float* dst = cb + ((kq - 2) * 2 + wn2) * 8192;
    for (int mi = 0; mi < 4; ++mi)
      for (int ni = 0; ni < 2; ++ni)
        for (int q4 = 0; q4 < 4; ++q4) {
          f32x4 v = {acc[mi][ni][q4 * 4 + 0], acc[mi][ni][q4 * 4 + 1],
                     acc[mi][ni][q4 * 4 + 2], acc[mi][ni][q4 * 4 + 3]};
          *(f32x4*)&dst[(((mi * 2 + ni) * 4 + q4) * 64 + ln) * 4] = v;
        }
  }
  __syncthreads();
  if (kq < 2) {
    const float* src = cb + (kq * 2 + wn2) * 8192;
    for (int mi = 0; mi < 4; ++mi)
      for (int ni = 0; ni < 2; ++ni)
        for (int q4 = 0; q4 < 4; ++q4) {
          f32x4 p = *(const f32x4*)&src[(((mi * 2 + ni) * 4 + q4) * 64 + ln) * 4];
          for (int e = 0; e < 4; ++e) acc[mi][ni][q4 * 4 + e] += p[e];
        }
  }
  __syncthreads();
  // round 2: kq=1 exports, kq=0 adds -> kq=0 holds full-K acc
  if (kq == 1) {
    float* dst = cb + wn2 * 8192;
    for (int mi = 0; mi < 4; ++mi)
      for (int ni = 0; ni < 2; ++ni)
        for (int q4 = 0; q4 < 4; ++q4) {
          f32x4 v = {acc[mi][ni][q4 * 4 + 0], acc[mi][ni][q4 * 4 + 1],
                     acc[mi][ni][q4 * 4 + 2], acc[mi][ni][q4 * 4 + 3]};
          *(f32x4*)&dst[(((mi * 2 + ni) * 4 + q4) * 64 + ln) * 4] = v;
        }
  }
  __syncthreads();
  if (kq == 0) {
    const float* src = cb + wn2 * 8192;
    for (int mi = 0; mi < 4; ++mi)
      for (int ni = 0; ni < 2; ++ni)
        for (int q4 = 0; q4 < 4; ++q4) {
          f32x4 p = *(const f32x4*)&src[(((mi * 2 + ni) * 4 + q4) * 64 + ln) * 4];
          for (int e = 0; e < 4; ++e) acc[mi][ni][q4 * 4 + e] += p[e];
        }
  }

  // epilogue in two 64-row halves; LSTM + fused heads  [reader verified r6/r7]
  for (int half = 0; half < 2; ++half) {
    __syncthreads();
    if (wv < 2) {                              // writer waves (kq=0, wn2=0/1)
      for (int mi2 = 0; mi2 < 2; ++mi2) {
        int mi = half * 2 + mi2;
        for (int ni = 0; ni < 2; ++ni) {
          int col = wn2 * 64 + ni * 32 + (ln & 31);
          int rbase = mi2 * 32 + 4 * (ln >> 5);
          for (int r = 0; r < 16; ++r) {
            int row = rbase + (r & 3) + 8 * (r >> 2);
            gt[row * 132 + col] = acc[mi][ni][r];
          }
        }
      }
    }
    __syncthreads();
    if ((wv >> 2) == half) {                   // 4 reader waves
      const int q = wv & 3;
      const int lrow = q * 16 + r16;           // 0..63
      const int bg = bm0 + half * 64 + lrow;
      const float x0 = x[bg * 2 + 0], x1 = x[bg * 2 + 1];
      const int hc0 = nt * 32 + quad * 8;
      const size_t pos = (((size_t)(bg >> 5)) * 128 + (hc0 >> 4)) * 512 +
                         ((hc0 >> 3) & 1) * 256 + (bg & 31) * 8;
      float cv[8]; u16 hv[8];
      float s0 = 0.f, s1 = 0.f, s2 = 0.f;
      const float4* epi4 = (const float4*)epi;
      for (int j = 0; j < 8; ++j) {
        int col = quad * 32 + j * 4;
        float4 g4 = *(const float4*)&gt[lrow * 132 + col];
        float4 e0 = epi4[nt * 128 + col + 0];
        float4 e1 = epi4[nt * 128 + col + 1];
        float4 e2 = epi4[nt * 128 + col + 2];
        float4 e3 = epi4[nt * 128 + col + 3];
        float gi = g4.x + e0.x + x0 * e0.y + x1 * e0.z;
        float gf = g4.y + e1.x + x0 * e1.y + x1 * e1.z;
        float gg = g4.z + e2.x + x0 * e2.y + x1 * e2.z;
        float go = g4.w + e3.x + x0 * e3.y + x1 * e3.z;
        float si = 1.f / (1.f + __expf(-gi));
        float sf = 1.f / (1.f + __expf(-gf));
        float so = 1.f / (1.f + __expf(-go));
        float cn = sf * c[pos + j] + si * tanhf(gg);
        cv[j] = cn;
        float hf = so * tanhf(cn);
        hv[j] = f2b(hf);
        s0 += hf * W_out[hc0 + j];
        s1 += hf * W_out[H_DIM + hc0 + j];
        s2 += hf * W_stop[hc0 + j];
      }
      *(float4*)&c[pos + 0] = *(float4*)&cv[0];
      *(float4*)&c[pos + 4] = *(float4*)&cv[4];
      *(ushort4*)&h_out[pos + 0] = *(ushort4*)&hv[0];
      *(ushort4*)&h_out[pos + 4] = *(ushort4*)&hv[4];
      s0 += __shfl_xor(s0, 16); s1 += __shfl_xor(s1, 16); s2 += __shfl_xor(s2, 16);
      s0 += __shfl_xor(s0, 32); s1 += __shfl_xor(s1, 32); s2 += __shfl_xor(s2, 32);
      if (quad == 0) {
        atomicAdd(&coords[((size_t)bg * T_DIM + trow) * 2 + 0], s0);
        atomicAdd(&coords[((size_t)bg * T_DIM + trow) * 2 + 1], s1);
        atomicAdd(&stops[(size_t)bg * T_DIM + trow], s2);
      }
    }
  }
}

extern "C" void kernel_launch(void* const* d_in, const int* in_sizes, int n_in,
                              void* d_out, int out_size, void* d_ws, size_t ws_size,
                              hipStream_t stream) {
  const float* embedding = (const float*)d_in[0];
  const float* W_embed   = (const float*)d_in[2];
  const float* b_embed   = (const float*)d_in[3];
  const float* W_ih      = (const float*)d_in[4];
  const float* b_ih      = (const float*)d_in[5];
  const float* W_hh      = (const float*)d_in[6];
  const float* b_hh      = (const float*)d_in[7];
  const float* W_out     = (const float*)d_in[8];
  const float* b_out     = (const float*)d_in[9];
  const float* W_stop    = (const float*)d_in[10];
  const float* b_stop    = (const float*)d_in[11];

  float* coords = (float*)d_out;
  float* stops  = (float*)d_out + (size_t)B_DIM * T_DIM * 2;

  char* ws = (char*)d_ws;
  u16* W_z     = (u16*)ws;   ws += (size_t)G4H * H_DIM * 2;    // 32 MB
  u16* W_emb_b = (u16*)ws;   ws += (size_t)H_DIM * E_DIM * 2;  // 8 MB
  u16* emb_b   = (u16*)ws;   ws += (size_t)B_DIM * E_DIM * 2;  // 2 MB
  float* h0pre = (float*)ws; ws += (size_t)B_DIM * H_DIM * 4;  // 4 MB
  float* epi   = (float*)ws; ws += (size_t)G4H * 4 * 4;        // 128 KB
  float* cbuf  = (float*)ws; ws += (size_t)B_DIM * H_DIM * 4;  // 4 MB
  u16* hbuf0   = (u16*)ws;   ws += (size_t)B_DIM * H_DIM * 2;  // 2 MB
  u16* hbuf1   = (u16*)ws;   ws += (size_t)B_DIM * H_DIM * 2;  // 2 MB
  float* xcorr = (float*)ws; ws += (size_t)B_DIM * 2 * 4;
  float* xzero = (float*)ws; ws += (size_t)B_DIM * 2 * 4;

  convert_bf16<<<(B_DIM * E_DIM / 4 + 255) / 256, 256, 0, stream>>>(embedding, emb_b, B_DIM * E_DIM / 4);
  convert_bf16<<<(H_DIM * E_DIM / 4 + 255) / 256, 256, 0, stream>>>(W_embed, W_emb_b, H_DIM * E_DIM / 4);
  build_weff<<<(G4H * H_DIM / 8) / 256, 256, 0, stream>>>(W_hh, W_ih, W_out, W_z);
  build_epi<<<G4H / 256, 256, 0, stream>>>(b_ih, b_hh, W_ih, b_out, epi);
  init_out<<<(B_DIM * T_DIM) / 256, 256, 0, stream>>>(b_out, b_stop, coords, stops);

  gemm_bt<<<dim3(H_DIM / BN, B_DIM / BM), 256, 0, stream>>>(emb_b, W_emb_b, h0pre,
                                                            B_DIM, H_DIM, E_DIM);
  init_state<<<(B_DIM * H_DIM) / 256, 256, 0, stream>>>(h0pre, b_embed, hbuf0, cbuf, xzero);
  calc_xcorr<<<B_DIM, 64, 0, stream>>>(h0pre, b_embed, W_out, b_out, xcorr);

  for (int t = 0; t < T_DIM; ++t) {
    u16* h_in  = (t & 1) ? hbuf1 : hbuf0;
    u16* h_out = (t & 1) ? hbuf0 : hbuf1;
    const float* xv = (t == 0) ? xcorr : xzero;
    gemm_lstm<<<256, 512, 0, stream>>>(h_in, W_z, epi, xv, cbuf, h_out,
                                       W_out, W_stop, coords, stops, t);
  }
  finalize_stops<<<(B_DIM * T_DIM) / 256, 256, 0, stream>>>(stops);
}

// Round 9
// 8252.100 us; speedup vs baseline: 1.0281x; 1.0281x over previous
//
#include <hip/hip_runtime.h>
#include <stdint.h>

#define E_DIM 2048
#define H_DIM 2048
#define B_DIM 512
#define T_DIM 256
#define G4H   8192  // 4*H

typedef unsigned short u16;
typedef __attribute__((ext_vector_type(8))) short bf16x8;
typedef __attribute__((ext_vector_type(4))) float f32x4;

__device__ inline u16 f2b(float f) {
  union { float f; uint32_t i; } v; v.f = f;
  uint32_t u = v.i;
  return (u16)((u + 0x7FFFu + ((u >> 16) & 1u)) >> 16);  // RNE
}
__device__ inline float b2f(u16 u) {
  union { uint32_t i; float f; } v; v.i = ((uint32_t)u) << 16; return v.f;
}

__global__ __launch_bounds__(256) void convert_bf16(const float* __restrict__ s,
                                                    u16* __restrict__ d, int n4) {
  int i = blockIdx.x * 256 + threadIdx.x;
  if (i < n4) {
    float4 f = ((const float4*)s)[i];
    ushort4 o;
    o.x = f2b(f.x); o.y = f2b(f.y); o.z = f2b(f.z); o.w = f2b(f.w);
    ((ushort4*)d)[i] = o;
  }
}

// W_eff = W_hh + W_ih @ W_out (rank-2 fold), MFMA-B-fragment order. [verified r5-r7]
__global__ __launch_bounds__(256) void build_weff(const float* __restrict__ W,
                                                  const float* __restrict__ W_ih,
                                                  const float* __restrict__ W_out,
                                                  u16* __restrict__ Wz) {
  int id = blockIdx.x * 256 + threadIdx.x;     // chunk id, total 2M
  int lane = id & 63;
  int k32  = (id >> 6) & 63;
  int n16  = id >> 12;
  int np = n16 * 16 + (lane & 15);
  int k  = k32 * 32 + (lane >> 4) * 8;
  int g = np & 3, jrow = np >> 2;
  int src = g * H_DIM + jrow;
  float wi0 = W_ih[src * 2 + 0], wi1 = W_ih[src * 2 + 1];
  const float* sw = W + (size_t)src * H_DIM + k;
  u16 out[8];
  for (int j = 0; j < 8; ++j) {
    float v = sw[j] + wi0 * W_out[k + j] + wi1 * W_out[H_DIM + k + j];
    out[j] = f2b(v);
  }
  u16* dst = Wz + (size_t)id * 8;
  *(ushort4*)(dst) = *(ushort4*)&out[0];
  *(ushort4*)(dst + 4) = *(ushort4*)&out[4];
}

// epi[n'] = {b_ih+b_hh+b_out@W_ih^T, W_ih[:,0], W_ih[:,1], 0}   [verified r5-r7]
__global__ __launch_bounds__(256) void build_epi(const float* __restrict__ b_ih,
                                                 const float* __restrict__ b_hh,
                                                 const float* __restrict__ W_ih,
                                                 const float* __restrict__ b_out,
                                                 float* __restrict__ epi) {
  int np = blockIdx.x * 256 + threadIdx.x;
  int src = (np & 3) * H_DIM + (np >> 2);
  float wi0 = W_ih[src * 2 + 0], wi1 = W_ih[src * 2 + 1];
  float4 e;
  e.x = b_ih[src] + b_hh[src] + b_out[0] * wi0 + b_out[1] * wi1;
  e.y = wi0;
  e.z = wi1;
  e.w = 0.f;
  ((float4*)epi)[np] = e;
}

// ---- plain GEMM (h0 path, runs once) ----
#define BM 64
#define BN 128
#define BK 32
__global__ __launch_bounds__(256) void gemm_bt(const u16* __restrict__ A,
                                               const u16* __restrict__ Bm,
                                               float* __restrict__ C,
                                               int M, int N, int K) {
  __shared__ u16 sA[BM * BK];
  __shared__ u16 sB[BN * BK];
  const int t = threadIdx.x;
  const int bm0 = blockIdx.y * BM, bn0 = blockIdx.x * BN;
  const int wave = t >> 6, lane = t & 63;
  const int wm = (wave >> 1) * 32, wn = (wave & 1) * 64;
  const int r16 = lane & 15, quad = lane >> 4;

  f32x4 acc[2][4];
  const f32x4 z = {0.f, 0.f, 0.f, 0.f};
  for (int i = 0; i < 2; ++i)
    for (int j = 0; j < 4; ++j) acc[i][j] = z;

  const int arow = t >> 2, acg = t & 3;

  for (int k0 = 0; k0 < K; k0 += BK) {
    __syncthreads();
    *(uint4*)&sA[arow * BK + acg * 8] =
        *(const uint4*)&A[(size_t)(bm0 + arow) * K + k0 + acg * 8];
    for (int i = 0; i < 2; ++i) {
      int c = t + 256 * i;
      int row = c >> 2, cg = c & 3;
      *(uint4*)&sB[row * BK + cg * 8] =
          *(const uint4*)&Bm[(size_t)(bn0 + row) * K + k0 + cg * 8];
    }
    __syncthreads();
    bf16x8 af[2], bfr[4];
    for (int mt = 0; mt < 2; ++mt)
      af[mt] = *(const bf16x8*)&sA[(wm + mt * 16 + r16) * BK + quad * 8];
    for (int nt = 0; nt < 4; ++nt)
      bfr[nt] = *(const bf16x8*)&sB[(wn + nt * 16 + r16) * BK + quad * 8];
    for (int mt = 0; mt < 2; ++mt)
      for (int nt = 0; nt < 4; ++nt)
        acc[mt][nt] = __builtin_amdgcn_mfma_f32_16x16x32_bf16(af[mt], bfr[nt],
                                                              acc[mt][nt], 0, 0, 0);
  }
  for (int mt = 0; mt < 2; ++mt)
    for (int nt = 0; nt < 4; ++nt) {
      int row = bm0 + wm + mt * 16 + quad * 4;
      int col = bn0 + wn + nt * 16 + r16;
      for (int r = 0; r < 4; ++r)
        C[(size_t)(row + r) * N + col] = acc[mt][nt][r];
    }
}

// h0pre + b_embed -> h fragment layout; c=0; xzero=0.   [verified r3-r7]
__global__ __launch_bounds__(256) void init_state(const float* __restrict__ h0pre,
                                                  const float* __restrict__ b_embed,
                                                  u16* __restrict__ h,
                                                  float* __restrict__ c,
                                                  float* __restrict__ xzero) {
  int idx = blockIdx.x * 256 + threadIdx.x;  // B*H
  int bg = idx >> 11, k = idx & (H_DIM - 1);
  float v = h0pre[idx] + b_embed[k];
  size_t chunk = (((size_t)(bg >> 4)) * 64 + (k >> 5)) * 64 + ((k >> 3) & 3) * 16 + (bg & 15);
  size_t pos = chunk * 8 + (k & 7);
  h[pos] = f2b(v);
  c[pos] = 0.f;
  if (idx < B_DIM * 2) xzero[idx] = 0.f;
}

// xcorr[m] = -(h0[m] @ W_out^T + b_out)   [verified r5-r7]
__global__ __launch_bounds__(64) void calc_xcorr(const float* __restrict__ h0pre,
                                                 const float* __restrict__ b_embed,
                                                 const float* __restrict__ W_out,
                                                 const float* __restrict__ b_out,
                                                 float* __restrict__ xc) {
  int m = blockIdx.x, ln = threadIdx.x;
  float s0 = 0.f, s1 = 0.f;
  for (int k = ln; k < H_DIM; k += 64) {
    float hv = h0pre[(size_t)m * H_DIM + k] + b_embed[k];
    s0 += hv * W_out[k];
    s1 += hv * W_out[H_DIM + k];
  }
  for (int off = 32; off > 0; off >>= 1) {
    s0 += __shfl_down(s0, off);
    s1 += __shfl_down(s1, off);
  }
  if (ln == 0) {
    xc[m * 2 + 0] = -(s0 + b_out[0]);
    xc[m * 2 + 1] = -(s1 + b_out[1]);
  }
}

__global__ __launch_bounds__(256) void init_out(const float* __restrict__ b_out,
                                                const float* __restrict__ b_stop,
                                                float* __restrict__ coords,
                                                float* __restrict__ stops) {
  int i = blockIdx.x * 256 + threadIdx.x;      // B*T
  coords[i * 2 + 0] = b_out[0];
  coords[i * 2 + 1] = b_out[1];
  stops[i] = b_stop[0];
}

__global__ __launch_bounds__(256) void finalize_stops(float* __restrict__ stops) {
  int i = blockIdx.x * 256 + threadIdx.x;      // B*T
  stops[i] = 1.f / (1.f + __expf(-stops[i]));
}

// ---- fused step: r7 structure + wave phase rotation + MFMA/VMEM interleave ----
// 8 waves: wn2 = wv&1 (n-half), kq = wv>>1 (K quarter).
// Each wave walks its 16 k-chunks rotated by 2*wv so SIMD partners (wv, wv+4)
// are offset by 8 chunks — de-phase-locks the load bursts. sched_group_barrier
// forces ~3 loads per 8 MFMAs (AITER-style 1:1-ish interleave).
__global__ __launch_bounds__(512) void gemm_lstm(const u16* __restrict__ hA,
                                                 const u16* __restrict__ Wz,
                                                 const float* __restrict__ epi,
                                                 const float* __restrict__ x,
                                                 float* __restrict__ c,
                                                 u16* __restrict__ h_out,
                                                 const float* __restrict__ W_out,
                                                 const float* __restrict__ W_stop,
                                                 float* __restrict__ coords,
                                                 float* __restrict__ stops,
                                                 int trow) {
  __shared__ char smem[131072];                // combine bufs; gt aliased
  float* cb = (float*)smem;
  float* gt = (float*)smem;                    // 64 x 132 f32 epilogue tile

  const int bid = blockIdx.x;
  const int nt = (bid & 7) * 8 + ((bid >> 3) & 7);   // XCD-pinned n-tile
  const int mt = bid >> 6;
  const int bm0 = mt * 128;

  const int t = threadIdx.x, wv = t >> 6, ln = t & 63;
  const int wn2 = wv & 1, kq = wv >> 1;
  const int r16 = ln & 15, quad = ln >> 4;
  const int phase = wv * 2;                    // SIMD partners offset by 8

  // fragment pointers; elem offset within tile = k32*512 + ln*8 (u16 units)
  const u16* pA[8];
  const u16* pB[4];
  for (int i = 0; i < 8; ++i)
    pA[i] = hA + (size_t)((bm0 >> 4) + i) * 32768 + (size_t)(kq * 16) * 512 + ln * 8;
  for (int i = 0; i < 4; ++i)
    pB[i] = Wz + (size_t)(nt * 8 + wn2 * 4 + i) * 32768 + (size_t)(kq * 16) * 512 + ln * 8;

  f32x4 acc[8][4];
  const f32x4 z = {0.f, 0.f, 0.f, 0.f};
  for (int i = 0; i < 8; ++i)
    for (int j = 0; j < 4; ++j) acc[i][j] = z;

  bf16x8 af[2][8], bf[2][4];
  {
    const size_t off0 = (size_t)(phase & 15) * 512;
    for (int i = 0; i < 8; ++i) af[0][i] = *(const bf16x8*)(pA[i] + off0);
    for (int i = 0; i < 4; ++i) bf[0][i] = *(const bf16x8*)(pB[i] + off0);
  }

#pragma unroll 2
  for (int kk = 0; kk < 16; ++kk) {
    const int cu = kk & 1;
    if (kk < 15) {
      const int nx = cu ^ 1;
      const size_t off = (size_t)((kk + 1 + phase) & 15) * 512;
      for (int i = 0; i < 8; ++i) af[nx][i] = *(const bf16x8*)(pA[i] + off);
      for (int i = 0; i < 4; ++i) bf[nx][i] = *(const bf16x8*)(pB[i] + off);
    }
    for (int mi = 0; mi < 8; ++mi)
      for (int ni = 0; ni < 4; ++ni)
        acc[mi][ni] = __builtin_amdgcn_mfma_f32_16x16x32_bf16(af[cu][mi], bf[cu][ni],
                                                              acc[mi][ni], 0, 0, 0);
    // interleave: 4 x (3 VMEM_READ, 8 MFMA) per kk
    __builtin_amdgcn_sched_group_barrier(0x020, 3, 0);
    __builtin_amdgcn_sched_group_barrier(0x008, 8, 0);
    __builtin_amdgcn_sched_group_barrier(0x020, 3, 0);
    __builtin_amdgcn_sched_group_barrier(0x008, 8, 0);
    __builtin_amdgcn_sched_group_barrier(0x020, 3, 0);
    __builtin_amdgcn_sched_group_barrier(0x008, 8, 0);
    __builtin_amdgcn_sched_group_barrier(0x020, 3, 0);
    __builtin_amdgcn_sched_group_barrier(0x008, 8, 0);
  }

  // K-combine: round 1: kq 2,3 export (4 x 32 KB), kq 0,1 add   [verified r7]
  if (kq >= 2) {
    float* dst = cb + ((kq - 2) * 2 + wn2) * 8192;
    for (int mi = 0; mi < 8; ++mi)
      for (int ni = 0; ni < 4; ++ni)
        *(f32x4*)&dst[((mi * 4 + ni) * 64 + ln) * 4] = acc[mi][ni];
  }
  __syncthreads();
  if (kq < 2) {
    const float* src = cb + (kq * 2 + wn2) * 8192;
    for (int mi = 0; mi < 8; ++mi)
      for (int ni = 0; ni < 4; ++ni)
        acc[mi][ni] += *(const f32x4*)&src[((mi * 4 + ni) * 64 + ln) * 4];
  }
  __syncthreads();
  // round 2: kq=1 exports, kq=0 adds -> kq=0 holds full-K acc
  if (kq == 1) {
    float* dst = cb + wn2 * 8192;
    for (int mi = 0; mi < 8; ++mi)
      for (int ni = 0; ni < 4; ++ni)
        *(f32x4*)&dst[((mi * 4 + ni) * 64 + ln) * 4] = acc[mi][ni];
  }
  __syncthreads();
  if (kq == 0) {
    const float* src = cb + wn2 * 8192;
    for (int mi = 0; mi < 8; ++mi)
      for (int ni = 0; ni < 4; ++ni)
        acc[mi][ni] += *(const f32x4*)&src[((mi * 4 + ni) * 64 + ln) * 4];
  }

  // epilogue in two 64-row halves; LSTM + fused heads   [verified r6/r7]
  for (int half = 0; half < 2; ++half) {
    __syncthreads();
    if (wv < 2) {                              // writer waves (kq=0, wn2=0/1)
      for (int mi = 0; mi < 4; ++mi)
        for (int ni = 0; ni < 4; ++ni) {
          int row = mi * 16 + quad * 4;        // local 0..63
          int col = wn2 * 64 + ni * 16 + r16;  // 0..127
          f32x4 v = acc[half * 4 + mi][ni];
          for (int r = 0; r < 4; ++r)
            gt[(row + r) * 132 + col] = v[r];
        }
    }
    __syncthreads();
    if ((wv >> 2) == half) {                   // 4 reader waves
      const int q = wv & 3;
      const int lrow = q * 16 + r16;           // 0..63
      const int bg = bm0 + half * 64 + lrow;
      const float x0 = x[bg * 2 + 0], x1 = x[bg * 2 + 1];
      const size_t chunk = (((size_t)(bg >> 4)) * 64 + nt) * 64 + ln;
      const int hc0 = nt * 32 + quad * 8;
      float cv[8]; u16 hv[8];
      float s0 = 0.f, s1 = 0.f, s2 = 0.f;
      const float4* epi4 = (const float4*)epi;
      for (int j = 0; j < 8; ++j) {
        int col = quad * 32 + j * 4;
        float4 g4 = *(const float4*)&gt[lrow * 132 + col];
        float4 e0 = epi4[nt * 128 + col + 0];
        float4 e1 = epi4[nt * 128 + col + 1];
        float4 e2 = epi4[nt * 128 + col + 2];
        float4 e3 = epi4[nt * 128 + col + 3];
        float gi = g4.x + e0.x + x0 * e0.y + x1 * e0.z;
        float gf = g4.y + e1.x + x0 * e1.y + x1 * e1.z;
        float gg = g4.z + e2.x + x0 * e2.y + x1 * e2.z;
        float go = g4.w + e3.x + x0 * e3.y + x1 * e3.z;
        float si = 1.f / (1.f + __expf(-gi));
        float sf = 1.f / (1.f + __expf(-gf));
        float so = 1.f / (1.f + __expf(-go));
        float cn = sf * c[chunk * 8 + j] + si * tanhf(gg);
        cv[j] = cn;
        float hf = so * tanhf(cn);
        hv[j] = f2b(hf);
        s0 += hf * W_out[hc0 + j];
        s1 += hf * W_out[H_DIM + hc0 + j];
        s2 += hf * W_stop[hc0 + j];
      }
      *(float4*)&c[chunk * 8 + 0] = *(float4*)&cv[0];
      *(float4*)&c[chunk * 8 + 4] = *(float4*)&cv[4];
      *(ushort4*)&h_out[chunk * 8 + 0] = *(ushort4*)&hv[0];
      *(ushort4*)&h_out[chunk * 8 + 4] = *(ushort4*)&hv[4];
      s0 += __shfl_xor(s0, 16); s1 += __shfl_xor(s1, 16); s2 += __shfl_xor(s2, 16);
      s0 += __shfl_xor(s0, 32); s1 += __shfl_xor(s1, 32); s2 += __shfl_xor(s2, 32);
      if (quad == 0) {
        atomicAdd(&coords[((size_t)bg * T_DIM + trow) * 2 + 0], s0);
        atomicAdd(&coords[((size_t)bg * T_DIM + trow) * 2 + 1], s1);
        atomicAdd(&stops[(size_t)bg * T_DIM + trow], s2);
      }
    }
  }
}

extern "C" void kernel_launch(void* const* d_in, const int* in_sizes, int n_in,
                              void* d_out, int out_size, void* d_ws, size_t ws_size,
                              hipStream_t stream) {
  const float* embedding = (const float*)d_in[0];
  const float* W_embed   = (const float*)d_in[2];
  const float* b_embed   = (const float*)d_in[3];
  const float* W_ih      = (const float*)d_in[4];
  const float* b_ih      = (const float*)d_in[5];
  const float* W_hh      = (const float*)d_in[6];
  const float* b_hh      = (const float*)d_in[7];
  const float* W_out     = (const float*)d_in[8];
  const float* b_out     = (const float*)d_in[9];
  const float* W_stop    = (const float*)d_in[10];
  const float* b_stop    = (const float*)d_in[11];

  float* coords = (float*)d_out;
  float* stops  = (float*)d_out + (size_t)B_DIM * T_DIM * 2;

  char* ws = (char*)d_ws;
  u16* W_z     = (u16*)ws;   ws += (size_t)G4H * H_DIM * 2;    // 32 MB
  u16* W_emb_b = (u16*)ws;   ws += (size_t)H_DIM * E_DIM * 2;  // 8 MB
  u16* emb_b   = (u16*)ws;   ws += (size_t)B_DIM * E_DIM * 2;  // 2 MB
  float* h0pre = (float*)ws; ws += (size_t)B_DIM * H_DIM * 4;  // 4 MB
  float* epi   = (float*)ws; ws += (size_t)G4H * 4 * 4;        // 128 KB
  float* cbuf  = (float*)ws; ws += (size_t)B_DIM * H_DIM * 4;  // 4 MB
  u16* hbuf0   = (u16*)ws;   ws += (size_t)B_DIM * H_DIM * 2;  // 2 MB
  u16* hbuf1   = (u16*)ws;   ws += (size_t)B_DIM * H_DIM * 2;  // 2 MB
  float* xcorr = (float*)ws; ws += (size_t)B_DIM * 2 * 4;
  float* xzero = (float*)ws; ws += (size_t)B_DIM * 2 * 4;

  convert_bf16<<<(B_DIM * E_DIM / 4 + 255) / 256, 256, 0, stream>>>(embedding, emb_b, B_DIM * E_DIM / 4);
  convert_bf16<<<(H_DIM * E_DIM / 4 + 255) / 256, 256, 0, stream>>>(W_embed, W_emb_b, H_DIM * E_DIM / 4);
  build_weff<<<(G4H * H_DIM / 8) / 256, 256, 0, stream>>>(W_hh, W_ih, W_out, W_z);
  build_epi<<<G4H / 256, 256, 0, stream>>>(b_ih, b_hh, W_ih, b_out, epi);
  init_out<<<(B_DIM * T_DIM) / 256, 256, 0, stream>>>(b_out, b_stop, coords, stops);

  gemm_bt<<<dim3(H_DIM / BN, B_DIM / BM), 256, 0, stream>>>(emb_b, W_emb_b, h0pre,
                                                            B_DIM, H_DIM, E_DIM);
  init_state<<<(B_DIM * H_DIM) / 256, 256, 0, stream>>>(h0pre, b_embed, hbuf0, cbuf, xzero);
  calc_xcorr<<<B_DIM, 64, 0, stream>>>(h0pre, b_embed, W_out, b_out, xcorr);

  for (int t = 0; t < T_DIM; ++t) {
    u16* h_in  = (t & 1) ? hbuf1 : hbuf0;
    u16* h_out = (t & 1) ? hbuf0 : hbuf1;
    const float* xv = (t == 0) ? xcorr : xzero;
    gemm_lstm<<<256, 512, 0, stream>>>(h_in, W_z, epi, xv, cbuf, h_out,
                                       W_out, W_stop, coords, stops, t);
  }
  finalize_stops<<<(B_DIM * T_DIM) / 256, 256, 0, stream>>>(stops);
}

// Round 10
// 8054.851 us; speedup vs baseline: 1.0533x; 1.0245x over previous
//
#include <hip/hip_runtime.h>
#include <stdint.h>

#define E_DIM 2048
#define H_DIM 2048
#define B_DIM 512
#define T_DIM 256
#define G4H   8192  // 4*H

typedef unsigned short u16;
typedef __attribute__((ext_vector_type(8))) short bf16x8;
typedef __attribute__((ext_vector_type(4))) float f32x4;

__device__ inline u16 f2b(float f) {
  union { float f; uint32_t i; } v; v.f = f;
  uint32_t u = v.i;
  return (u16)((u + 0x7FFFu + ((u >> 16) & 1u)) >> 16);  // RNE
}
__device__ inline float b2f(u16 u) {
  union { uint32_t i; float f; } v; v.i = ((uint32_t)u) << 16; return v.f;
}

__global__ __launch_bounds__(256) void convert_bf16(const float* __restrict__ s,
                                                    u16* __restrict__ d, int n4) {
  int i = blockIdx.x * 256 + threadIdx.x;
  if (i < n4) {
    float4 f = ((const float4*)s)[i];
    ushort4 o;
    o.x = f2b(f.x); o.y = f2b(f.y); o.z = f2b(f.z); o.w = f2b(f.w);
    ((ushort4*)d)[i] = o;
  }
}

// W_eff = W_hh + W_ih @ W_out (rank-2 fold), MFMA-B-fragment order. [verified r5-r9]
__global__ __launch_bounds__(256) void build_weff(const float* __restrict__ W,
                                                  const float* __restrict__ W_ih,
                                                  const float* __restrict__ W_out,
                                                  u16* __restrict__ Wz) {
  int id = blockIdx.x * 256 + threadIdx.x;     // chunk id, total 2M
  int lane = id & 63;
  int k32  = (id >> 6) & 63;
  int n16  = id >> 12;
  int np = n16 * 16 + (lane & 15);
  int k  = k32 * 32 + (lane >> 4) * 8;
  int g = np & 3, jrow = np >> 2;
  int src = g * H_DIM + jrow;
  float wi0 = W_ih[src * 2 + 0], wi1 = W_ih[src * 2 + 1];
  const float* sw = W + (size_t)src * H_DIM + k;
  u16 out[8];
  for (int j = 0; j < 8; ++j) {
    float v = sw[j] + wi0 * W_out[k + j] + wi1 * W_out[H_DIM + k + j];
    out[j] = f2b(v);
  }
  u16* dst = Wz + (size_t)id * 8;
  *(ushort4*)(dst) = *(ushort4*)&out[0];
  *(ushort4*)(dst + 4) = *(ushort4*)&out[4];
}

// epi[n'] = {b_ih+b_hh+b_out@W_ih^T, W_ih[:,0], W_ih[:,1], 0}   [verified r5-r9]
__global__ __launch_bounds__(256) void build_epi(const float* __restrict__ b_ih,
                                                 const float* __restrict__ b_hh,
                                                 const float* __restrict__ W_ih,
                                                 const float* __restrict__ b_out,
                                                 float* __restrict__ epi) {
  int np = blockIdx.x * 256 + threadIdx.x;
  int src = (np & 3) * H_DIM + (np >> 2);
  float wi0 = W_ih[src * 2 + 0], wi1 = W_ih[src * 2 + 1];
  float4 e;
  e.x = b_ih[src] + b_hh[src] + b_out[0] * wi0 + b_out[1] * wi1;
  e.y = wi0;
  e.z = wi1;
  e.w = 0.f;
  ((float4*)epi)[np] = e;
}

// ---- plain GEMM (h0 path, runs once) ----
#define BM 64
#define BN 128
#define BK 32
__global__ __launch_bounds__(256) void gemm_bt(const u16* __restrict__ A,
                                               const u16* __restrict__ Bm,
                                               float* __restrict__ C,
                                               int M, int N, int K) {
  __shared__ u16 sA[BM * BK];
  __shared__ u16 sB[BN * BK];
  const int t = threadIdx.x;
  const int bm0 = blockIdx.y * BM, bn0 = blockIdx.x * BN;
  const int wave = t >> 6, lane = t & 63;
  const int wm = (wave >> 1) * 32, wn = (wave & 1) * 64;
  const int r16 = lane & 15, quad = lane >> 4;

  f32x4 acc[2][4];
  const f32x4 z = {0.f, 0.f, 0.f, 0.f};
  for (int i = 0; i < 2; ++i)
    for (int j = 0; j < 4; ++j) acc[i][j] = z;

  const int arow = t >> 2, acg = t & 3;

  for (int k0 = 0; k0 < K; k0 += BK) {
    __syncthreads();
    *(uint4*)&sA[arow * BK + acg * 8] =
        *(const uint4*)&A[(size_t)(bm0 + arow) * K + k0 + acg * 8];
    for (int i = 0; i < 2; ++i) {
      int c = t + 256 * i;
      int row = c >> 2, cg = c & 3;
      *(uint4*)&sB[row * BK + cg * 8] =
          *(const uint4*)&Bm[(size_t)(bn0 + row) * K + k0 + cg * 8];
    }
    __syncthreads();
    bf16x8 af[2], bfr[4];
    for (int mt = 0; mt < 2; ++mt)
      af[mt] = *(const bf16x8*)&sA[(wm + mt * 16 + r16) * BK + quad * 8];
    for (int nt = 0; nt < 4; ++nt)
      bfr[nt] = *(const bf16x8*)&sB[(wn + nt * 16 + r16) * BK + quad * 8];
    for (int mt = 0; mt < 2; ++mt)
      for (int nt = 0; nt < 4; ++nt)
        acc[mt][nt] = __builtin_amdgcn_mfma_f32_16x16x32_bf16(af[mt], bfr[nt],
                                                              acc[mt][nt], 0, 0, 0);
  }
  for (int mt = 0; mt < 2; ++mt)
    for (int nt = 0; nt < 4; ++nt) {
      int row = bm0 + wm + mt * 16 + quad * 4;
      int col = bn0 + wn + nt * 16 + r16;
      for (int r = 0; r < 4; ++r)
        C[(size_t)(row + r) * N + col] = acc[mt][nt][r];
    }
}

// h0pre + b_embed -> h fragment layout; c=0; xzero=0.   [verified r3-r9]
__global__ __launch_bounds__(256) void init_state(const float* __restrict__ h0pre,
                                                  const float* __restrict__ b_embed,
                                                  u16* __restrict__ h,
                                                  float* __restrict__ c,
                                                  float* __restrict__ xzero) {
  int idx = blockIdx.x * 256 + threadIdx.x;  // B*H
  int bg = idx >> 11, k = idx & (H_DIM - 1);
  float v = h0pre[idx] + b_embed[k];
  size_t chunk = (((size_t)(bg >> 4)) * 64 + (k >> 5)) * 64 + ((k >> 3) & 3) * 16 + (bg & 15);
  size_t pos = chunk * 8 + (k & 7);
  h[pos] = f2b(v);
  c[pos] = 0.f;
  if (idx < B_DIM * 2) xzero[idx] = 0.f;
}

// xcorr[m] = -(h0[m] @ W_out^T + b_out)   [verified r5-r9]
__global__ __launch_bounds__(64) void calc_xcorr(const float* __restrict__ h0pre,
                                                 const float* __restrict__ b_embed,
                                                 const float* __restrict__ W_out,
                                                 const float* __restrict__ b_out,
                                                 float* __restrict__ xc) {
  int m = blockIdx.x, ln = threadIdx.x;
  float s0 = 0.f, s1 = 0.f;
  for (int k = ln; k < H_DIM; k += 64) {
    float hv = h0pre[(size_t)m * H_DIM + k] + b_embed[k];
    s0 += hv * W_out[k];
    s1 += hv * W_out[H_DIM + k];
  }
  for (int off = 32; off > 0; off >>= 1) {
    s0 += __shfl_down(s0, off);
    s1 += __shfl_down(s1, off);
  }
  if (ln == 0) {
    xc[m * 2 + 0] = -(s0 + b_out[0]);
    xc[m * 2 + 1] = -(s1 + b_out[1]);
  }
}

__global__ __launch_bounds__(256) void init_out(const float* __restrict__ b_out,
                                                const float* __restrict__ b_stop,
                                                float* __restrict__ coords,
                                                float* __restrict__ stops) {
  int i = blockIdx.x * 256 + threadIdx.x;      // B*T
  coords[i * 2 + 0] = b_out[0];
  coords[i * 2 + 1] = b_out[1];
  stops[i] = b_stop[0];
}

__global__ __launch_bounds__(256) void finalize_stops(float* __restrict__ stops) {
  int i = blockIdx.x * 256 + threadIdx.x;      // B*T
  stops[i] = 1.f / (1.f + __expf(-stops[i]));
}

// ---- fused step: 64x128 block, 64x64 wave tiles, 2 blocks/CU, 4 waves/SIMD ----
// Grid 512 = 8 mt x 64 nt (XCD-pinned). 8 waves: nh = wv&1, kq = wv>>1.
// Single-buffered frags + 64-VGPR acc -> <=128 VGPR (launch_bounds(512,4)),
// so 2 blocks/CU = 16 waves/CU = 4 waves/SIMD: TLP hides load latency.
__global__ __launch_bounds__(512, 4) void gemm_lstm(const u16* __restrict__ hA,
                                                    const u16* __restrict__ Wz,
                                                    const float* __restrict__ epi,
                                                    const float* __restrict__ x,
                                                    float* __restrict__ c,
                                                    u16* __restrict__ h_out,
                                                    const float* __restrict__ W_out,
                                                    const float* __restrict__ W_stop,
                                                    float* __restrict__ coords,
                                                    float* __restrict__ stops,
                                                    int trow) {
  __shared__ char smem[65536];                 // 4 x 16 KB combine bufs; gt aliased
  float* cb = (float*)smem;
  float* gt = (float*)smem;                    // 64 x 132 f32 epilogue tile

  const int bid = blockIdx.x;                  // 0..511
  const int nt = (bid & 7) * 8 + ((bid >> 3) & 7);   // 0..63, XCD-pinned
  const int mt = bid >> 6;                     // 0..7
  const int bm0 = mt * 64;

  const int t = threadIdx.x, wv = t >> 6, ln = t & 63;
  const int nh = wv & 1, kq = wv >> 1;
  const int r16 = ln & 15, quad = ln >> 4;

  // fragment base pointers (u16 units); chunk elem off = (tile16*64 + k32)*512 + ln*8
  const u16* pA = hA + ((size_t)(mt * 4) * 64 + (size_t)(kq * 16)) * 512 + ln * 8;
  const u16* pB = Wz + ((size_t)(nt * 8 + nh * 4) * 64 + (size_t)(kq * 16)) * 512 + ln * 8;

  f32x4 acc[4][4];
  const f32x4 z = {0.f, 0.f, 0.f, 0.f};
  for (int i = 0; i < 4; ++i)
    for (int j = 0; j < 4; ++j) acc[i][j] = z;

#pragma unroll 1
  for (int kk = 0; kk < 16; ++kk) {
    bf16x8 af[4], bf[4];
    for (int i = 0; i < 4; ++i) af[i] = *(const bf16x8*)(pA + (size_t)i * 32768);
    for (int i = 0; i < 4; ++i) bf[i] = *(const bf16x8*)(pB + (size_t)i * 32768);
    for (int mi = 0; mi < 4; ++mi)
      for (int ni = 0; ni < 4; ++ni)
        acc[mi][ni] = __builtin_amdgcn_mfma_f32_16x16x32_bf16(af[mi], bf[ni],
                                                              acc[mi][ni], 0, 0, 0);
    pA += 512;
    pB += 512;
  }

  // K-combine round 1: kq 2,3 export (4 x 16 KB), kq 0,1 add
  if (kq >= 2) {
    float* dst = cb + ((kq - 2) * 2 + nh) * 4096;
    for (int mi = 0; mi < 4; ++mi)
      for (int ni = 0; ni < 4; ++ni)
        *(f32x4*)&dst[((mi * 4 + ni) * 64 + ln) * 4] = acc[mi][ni];
  }
  __syncthreads();
  if (kq < 2) {
    const float* src = cb + (kq * 2 + nh) * 4096;
    for (int mi = 0; mi < 4; ++mi)
      for (int ni = 0; ni < 4; ++ni)
        acc[mi][ni] += *(const f32x4*)&src[((mi * 4 + ni) * 64 + ln) * 4];
  }
  __syncthreads();
  // round 2: kq=1 exports, kq=0 adds -> kq=0 (waves 0,1) holds full-K acc
  if (kq == 1) {
    float* dst = cb + nh * 4096;
    for (int mi = 0; mi < 4; ++mi)
      for (int ni = 0; ni < 4; ++ni)
        *(f32x4*)&dst[((mi * 4 + ni) * 64 + ln) * 4] = acc[mi][ni];
  }
  __syncthreads();
  if (kq == 0) {
    const float* src = cb + nh * 4096;
    for (int mi = 0; mi < 4; ++mi)
      for (int ni = 0; ni < 4; ++ni)
        acc[mi][ni] += *(const f32x4*)&src[((mi * 4 + ni) * 64 + ln) * 4];
  }

  // epilogue: single 64-row round; LSTM + fused heads   [pattern verified r6-r9]
  __syncthreads();
  if (wv < 2) {                                // writer waves (kq=0, nh=0/1)
    for (int mi = 0; mi < 4; ++mi)
      for (int ni = 0; ni < 4; ++ni) {
        int row = mi * 16 + quad * 4;          // local 0..63
        int col = nh * 64 + ni * 16 + r16;     // 0..127
        f32x4 v = acc[mi][ni];
        for (int r = 0; r < 4; ++r)
          gt[(row + r) * 132 + col] = v[r];
      }
  }
  __syncthreads();
  if (wv >= 4) {                               // 4 reader waves
    const int q = wv - 4;
    const int lrow = q * 16 + r16;             // 0..63
    const int bg = bm0 + lrow;
    const float x0 = x[bg * 2 + 0], x1 = x[bg * 2 + 1];
    const size_t chunk = (((size_t)(bg >> 4)) * 64 + nt) * 64 + ln;
    const int hc0 = nt * 32 + quad * 8;
    float cv[8]; u16 hv[8];
    float s0 = 0.f, s1 = 0.f, s2 = 0.f;
    const float4* epi4 = (const float4*)epi;
    for (int j = 0; j < 8; ++j) {
      int col = quad * 32 + j * 4;
      float4 g4 = *(const float4*)&gt[lrow * 132 + col];
      float4 e0 = epi4[nt * 128 + col + 0];
      float4 e1 = epi4[nt * 128 + col + 1];
      float4 e2 = epi4[nt * 128 + col + 2];
      float4 e3 = epi4[nt * 128 + col + 3];
      float gi = g4.x + e0.x + x0 * e0.y + x1 * e0.z;
      float gf = g4.y + e1.x + x0 * e1.y + x1 * e1.z;
      float gg = g4.z + e2.x + x0 * e2.y + x1 * e2.z;
      float go = g4.w + e3.x + x0 * e3.y + x1 * e3.z;
      float si = 1.f / (1.f + __expf(-gi));
      float sf = 1.f / (1.f + __expf(-gf));
      float so = 1.f / (1.f + __expf(-go));
      float cn = sf * c[chunk * 8 + j] + si * tanhf(gg);
      cv[j] = cn;
      float hf = so * tanhf(cn);
      hv[j] = f2b(hf);
      s0 += hf * W_out[hc0 + j];
      s1 += hf * W_out[H_DIM + hc0 + j];
      s2 += hf * W_stop[hc0 + j];
    }
    *(float4*)&c[chunk * 8 + 0] = *(float4*)&cv[0];
    *(float4*)&c[chunk * 8 + 4] = *(float4*)&cv[4];
    *(ushort4*)&h_out[chunk * 8 + 0] = *(ushort4*)&hv[0];
    *(ushort4*)&h_out[chunk * 8 + 4] = *(ushort4*)&hv[4];
    s0 += __shfl_xor(s0, 16); s1 += __shfl_xor(s1, 16); s2 += __shfl_xor(s2, 16);
    s0 += __shfl_xor(s0, 32); s1 += __shfl_xor(s1, 32); s2 += __shfl_xor(s2, 32);
    if (quad == 0) {
      atomicAdd(&coords[((size_t)bg * T_DIM + trow) * 2 + 0], s0);
      atomicAdd(&coords[((size_t)bg * T_DIM + trow) * 2 + 1], s1);
      atomicAdd(&stops[(size_t)bg * T_DIM + trow], s2);
    }
  }
}

extern "C" void kernel_launch(void* const* d_in, const int* in_sizes, int n_in,
                              void* d_out, int out_size, void* d_ws, size_t ws_size,
                              hipStream_t stream) {
  const float* embedding = (const float*)d_in[0];
  const float* W_embed   = (const float*)d_in[2];
  const float* b_embed   = (const float*)d_in[3];
  const float* W_ih      = (const float*)d_in[4];
  const float* b_ih      = (const float*)d_in[5];
  const float* W_hh      = (const float*)d_in[6];
  const float* b_hh      = (const float*)d_in[7];
  const float* W_out     = (const float*)d_in[8];
  const float* b_out     = (const float*)d_in[9];
  const float* W_stop    = (const float*)d_in[10];
  const float* b_stop    = (const float*)d_in[11];

  float* coords = (float*)d_out;
  float* stops  = (float*)d_out + (size_t)B_DIM * T_DIM * 2;

  char* ws = (char*)d_ws;
  u16* W_z     = (u16*)ws;   ws += (size_t)G4H * H_DIM * 2;    // 32 MB
  u16* W_emb_b = (u16*)ws;   ws += (size_t)H_DIM * E_DIM * 2;  // 8 MB
  u16* emb_b   = (u16*)ws;   ws += (size_t)B_DIM * E_DIM * 2;  // 2 MB
  float* h0pre = (float*)ws; ws += (size_t)B_DIM * H_DIM * 4;  // 4 MB
  float* epi   = (float*)ws; ws += (size_t)G4H * 4 * 4;        // 128 KB
  float* cbuf  = (float*)ws; ws += (size_t)B_DIM * H_DIM * 4;  // 4 MB
  u16* hbuf0   = (u16*)ws;   ws += (size_t)B_DIM * H_DIM * 2;  // 2 MB
  u16* hbuf1   = (u16*)ws;   ws += (size_t)B_DIM * H_DIM * 2;  // 2 MB
  float* xcorr = (float*)ws; ws += (size_t)B_DIM * 2 * 4;
  float* xzero = (float*)ws; ws += (size_t)B_DIM * 2 * 4;

  convert_bf16<<<(B_DIM * E_DIM / 4 + 255) / 256, 256, 0, stream>>>(embedding, emb_b, B_DIM * E_DIM / 4);
  convert_bf16<<<(H_DIM * E_DIM / 4 + 255) / 256, 256, 0, stream>>>(W_embed, W_emb_b, H_DIM * E_DIM / 4);
  build_weff<<<(G4H * H_DIM / 8) / 256, 256, 0, stream>>>(W_hh, W_ih, W_out, W_z);
  build_epi<<<G4H / 256, 256, 0, stream>>>(b_ih, b_hh, W_ih, b_out, epi);
  init_out<<<(B_DIM * T_DIM) / 256, 256, 0, stream>>>(b_out, b_stop, coords, stops);

  gemm_bt<<<dim3(H_DIM / BN, B_DIM / BM), 256, 0, stream>>>(emb_b, W_emb_b, h0pre,
                                                            B_DIM, H_DIM, E_DIM);
  init_state<<<(B_DIM * H_DIM) / 256, 256, 0, stream>>>(h0pre, b_embed, hbuf0, cbuf, xzero);
  calc_xcorr<<<B_DIM, 64, 0, stream>>>(h0pre, b_embed, W_out, b_out, xcorr);

  for (int t = 0; t < T_DIM; ++t) {
    u16* h_in  = (t & 1) ? hbuf1 : hbuf0;
    u16* h_out = (t & 1) ? hbuf0 : hbuf1;
    const float* xv = (t == 0) ? xcorr : xzero;
    gemm_lstm<<<512, 512, 0, stream>>>(h_in, W_z, epi, xv, cbuf, h_out,
                                       W_out, W_stop, coords, stops, t);
  }
  finalize_stops<<<(B_DIM * T_DIM) / 256, 256, 0, stream>>>(stops);
}